// Round 11
// baseline (382.628 us; speedup 1.0000x reference)
//
#include <hip/hip_runtime.h>

#define THREADS 256
#define KC 32

// ---- bf16 helpers ----
__device__ inline ushort f2bf(float v) {
    union { float f; unsigned u; } a; a.f = v;
    unsigned r = a.u + 0x7fff + ((a.u >> 16) & 1);
    return (ushort)(r >> 16);
}
__device__ inline unsigned pack2(float a, float b) {
    return (unsigned)f2bf(a) | ((unsigned)f2bf(b) << 16);
}
__device__ inline float bflo(unsigned v) {
    union { unsigned u; float f; } a; a.u = v << 16; return a.f;
}
__device__ inline float bfhi(unsigned v) {
    union { unsigned u; float f; } a; a.u = v & 0xffff0000u; return a.f;
}

// ---------- F1: interleaved [GEMM1 unscaled] x [deg+rank] + [cnt] ----------
// Roles interleaved by parity so both kinds are co-resident from t=0:
// odd bid < 2*gTile -> GEMM tile (bid>>1); everything else -> deg/cnt.
__global__ __launch_bounds__(THREADS) void
k_f1(const float* __restrict__ X, const float* __restrict__ W,
     ushort* __restrict__ C, int n, int fin, int nGemm,
     const int* __restrict__ dst, int* __restrict__ deg, int* __restrict__ rank,
     int E, int nDeg,
     const int* __restrict__ dict, float* __restrict__ cnt, int nCnt) {
    int bid = blockIdx.x, tid = threadIdx.x;
    bool isGemm = (bid & 1) && (bid >> 1) < nGemm;
    if (!isGemm) {
        int idx = (bid < 2 * nGemm) ? (bid >> 1) : (bid - nGemm);
        if (idx < nDeg) {
            int stride = nDeg * THREADS;
            for (int e = idx * THREADS + tid; e < E; e += stride)
                rank[e] = atomicAdd(&deg[dst[e]], 1);
        } else {
            int stride = nCnt * THREADS;
            for (int i = (idx - nDeg) * THREADS + tid; i < n; i += stride)
                atomicAdd(&cnt[dict[i]], 1.0f);
        }
        return;
    }
    // ---- GEMM role: C[r,c] = (X@W)[r,c] -> bf16 (unscaled) ----
    __shared__ float Xs[KC][68];
    __shared__ float Ws[KC][64];
    int r0  = (bid >> 1) * 64;
    int tx4 = (tid & 15) * 4;
    int ty4 = (tid >> 4) * 4;
    int sxr = tid >> 2, sxk = (tid & 3) * 4;
    int swk = tid >> 4, swc = (tid & 15) * 4;
    int xrow = r0 + sxr; if (xrow >= n) xrow = n - 1;
    const float* xptr = X + (size_t)xrow * fin;
    float4 acc0 = {0,0,0,0}, acc1 = {0,0,0,0}, acc2 = {0,0,0,0}, acc3 = {0,0,0,0};
    for (int kc = 0; kc < fin; kc += KC) {
        float4 xa = *(const float4*)(xptr + kc + sxk);
        float4 xb = *(const float4*)(xptr + kc + 16 + sxk);
        float4 wa = *(const float4*)(W + (size_t)(kc + swk) * 64 + swc);
        float4 wb = *(const float4*)(W + (size_t)(kc + swk + 16) * 64 + swc);
        __syncthreads();
        Xs[sxk + 0][sxr] = xa.x; Xs[sxk + 1][sxr] = xa.y;
        Xs[sxk + 2][sxr] = xa.z; Xs[sxk + 3][sxr] = xa.w;
        Xs[16 + sxk + 0][sxr] = xb.x; Xs[16 + sxk + 1][sxr] = xb.y;
        Xs[16 + sxk + 2][sxr] = xb.z; Xs[16 + sxk + 3][sxr] = xb.w;
        *(float4*)&Ws[swk][swc]      = wa;
        *(float4*)&Ws[swk + 16][swc] = wb;
        __syncthreads();
        #pragma unroll 8
        for (int k = 0; k < KC; ++k) {
            float4 a = *(const float4*)&Xs[k][ty4];
            float4 b = *(const float4*)&Ws[k][tx4];
            acc0.x = fmaf(a.x, b.x, acc0.x); acc0.y = fmaf(a.x, b.y, acc0.y);
            acc0.z = fmaf(a.x, b.z, acc0.z); acc0.w = fmaf(a.x, b.w, acc0.w);
            acc1.x = fmaf(a.y, b.x, acc1.x); acc1.y = fmaf(a.y, b.y, acc1.y);
            acc1.z = fmaf(a.y, b.z, acc1.z); acc1.w = fmaf(a.y, b.w, acc1.w);
            acc2.x = fmaf(a.z, b.x, acc2.x); acc2.y = fmaf(a.z, b.y, acc2.y);
            acc2.z = fmaf(a.z, b.z, acc2.z); acc2.w = fmaf(a.z, b.w, acc2.w);
            acc3.x = fmaf(a.w, b.x, acc3.x); acc3.y = fmaf(a.w, b.y, acc3.y);
            acc3.z = fmaf(a.w, b.z, acc3.z); acc3.w = fmaf(a.w, b.w, acc3.w);
        }
    }
    int row = r0 + ty4;
    #pragma unroll
    for (int r = 0; r < 4; ++r) {
        if (row + r >= n) break;
        float4 a = r == 0 ? acc0 : r == 1 ? acc1 : r == 2 ? acc2 : acc3;
        ushort4 o;
        o.x = f2bf(a.x); o.y = f2bf(a.y); o.z = f2bf(a.z); o.w = f2bf(a.w);
        *(ushort4*)(C + (size_t)(row + r) * 64 + tx4) = o;
    }
}

// ---------- scans ----------
__global__ void k_bsum(const int* __restrict__ deg, int* __restrict__ bsum, int n) {
    __shared__ int s[THREADS];
    int i = blockIdx.x * THREADS + threadIdx.x;
    s[threadIdx.x] = (i < n) ? deg[i] : 0;
    __syncthreads();
    for (int o = THREADS / 2; o; o >>= 1) {
        if (threadIdx.x < o) s[threadIdx.x] += s[threadIdx.x + o];
        __syncthreads();
    }
    if (threadIdx.x == 0) bsum[blockIdx.x] = s[0];
}

// single block of 512; nb <= 512 (nb = 391 here)
__global__ void k_bscan(int* __restrict__ bsum, int nb) {
    __shared__ int s[512];
    int v = (threadIdx.x < nb) ? bsum[threadIdx.x] : 0;
    s[threadIdx.x] = v;
    __syncthreads();
    for (int o = 1; o < 512; o <<= 1) {
        int t = (threadIdx.x >= (unsigned)o) ? s[threadIdx.x - o] : 0;
        __syncthreads();
        s[threadIdx.x] += t;
        __syncthreads();
    }
    if (threadIdx.x < nb) bsum[threadIdx.x] = s[threadIdx.x] - v;  // exclusive
}

__global__ void k_offsets(const int* __restrict__ deg, const int* __restrict__ bsum,
                          int* __restrict__ off, float* __restrict__ dinv, int n, int E) {
    __shared__ int s[THREADS];
    int i = blockIdx.x * THREADS + threadIdx.x;
    int v = (i < n) ? deg[i] : 0;
    s[threadIdx.x] = v;
    __syncthreads();
    for (int o = 1; o < THREADS; o <<= 1) {
        int t = (threadIdx.x >= (unsigned)o) ? s[threadIdx.x - o] : 0;
        __syncthreads();
        s[threadIdx.x] += t;
        __syncthreads();
    }
    if (i < n) {
        off[i] = bsum[blockIdx.x] + s[threadIdx.x] - v;
        dinv[i] = rsqrtf((float)v + 1.0f);
        if (i == n - 1) off[n] = E;
    }
}

// ---------- F2: [bucket] + [scale bufA rows by dinv] ----------
__global__ void k_f2(const int* __restrict__ src, const int* __restrict__ dst,
                     const int* __restrict__ rank, const int* __restrict__ off,
                     int* __restrict__ csr, int E,
                     ushort* __restrict__ A, const float* __restrict__ dinv, int n,
                     int nBkt, int nScale) {
    int bid = blockIdx.x, tid = threadIdx.x;
    if (bid < nBkt) {
        int stride = nBkt * THREADS;
        for (int e = bid * THREADS + tid; e < E; e += stride)
            csr[off[dst[e]] + rank[e]] = src[e];
    } else {
        int t = (bid - nBkt) * THREADS + tid;    // one uint4 (8 bf16) per thread
        if (t < n * 8) {
            float dn = dinv[t >> 3];
            uint4 v = *(const uint4*)(A + (size_t)t * 8);
            uint4 o;
            o.x = pack2(bflo(v.x) * dn, bfhi(v.x) * dn);
            o.y = pack2(bflo(v.y) * dn, bfhi(v.y) * dn);
            o.z = pack2(bflo(v.z) * dn, bfhi(v.z) * dn);
            o.w = pack2(bflo(v.w) * dn, bfhi(v.w) * dn);
            *(uint4*)(A + (size_t)t * 8) = o;
        }
    }
}

// ---------- MLP gather core: wave = 1 node, 8 rows/instr, csr prefetch ----------
__device__ inline void gather_sum8(const ushort* __restrict__ H,
                                   const int* __restrict__ csr,
                                   int node, int j, int end, int g, int q,
                                   float4& R0, float4& R1) {
    float4 A0 = {0,0,0,0}, B0 = {0,0,0,0}, A1 = {0,0,0,0}, B1 = {0,0,0,0};
    if (g == 0) {  // self row joins slot 0
        uint4 sv = *(const uint4*)(H + ((size_t)node << 6) + q * 8);
        A0.x += bflo(sv.x); A0.y += bfhi(sv.x); A0.z += bflo(sv.y); A0.w += bfhi(sv.y);
        B0.x += bflo(sv.z); B0.y += bfhi(sv.z); B0.z += bflo(sv.w); B0.w += bfhi(sv.w);
    }
    int p0 = 0, p1 = 0;
    if (j + 16 <= end) { p0 = csr[j + g]; p1 = csr[j + 8 + g]; }
    while (j + 16 <= end) {
        int s0 = p0, s1 = p1;
        int jn = j + 16;
        if (jn + 16 <= end) { p0 = csr[jn + g]; p1 = csr[jn + 8 + g]; }  // prefetch
        uint4 v0 = *(const uint4*)(H + ((size_t)s0 << 6) + q * 8);
        uint4 v1 = *(const uint4*)(H + ((size_t)s1 << 6) + q * 8);
        A0.x += bflo(v0.x); A0.y += bfhi(v0.x); A0.z += bflo(v0.y); A0.w += bfhi(v0.y);
        B0.x += bflo(v0.z); B0.y += bfhi(v0.z); B0.z += bflo(v0.w); B0.w += bfhi(v0.w);
        A1.x += bflo(v1.x); A1.y += bfhi(v1.x); A1.z += bflo(v1.y); A1.w += bfhi(v1.y);
        B1.x += bflo(v1.z); B1.y += bfhi(v1.z); B1.z += bflo(v1.w); B1.w += bfhi(v1.w);
        j = jn;
    }
    if (j + 8 <= end) {
        int s0 = csr[j + g];
        uint4 v0 = *(const uint4*)(H + ((size_t)s0 << 6) + q * 8);
        A0.x += bflo(v0.x); A0.y += bfhi(v0.x); A0.z += bflo(v0.y); A0.w += bfhi(v0.y);
        B0.x += bflo(v0.z); B0.y += bfhi(v0.z); B0.z += bflo(v0.w); B0.w += bfhi(v0.w);
        j += 8;
    }
    if (g < end - j) {
        int s1 = csr[j + g];
        uint4 v1 = *(const uint4*)(H + ((size_t)s1 << 6) + q * 8);
        A1.x += bflo(v1.x); A1.y += bfhi(v1.x); A1.z += bflo(v1.y); A1.w += bfhi(v1.y);
        B1.x += bflo(v1.z); B1.y += bfhi(v1.z); B1.z += bflo(v1.w); B1.w += bfhi(v1.w);
    }
    R0.x = A0.x + A1.x; R0.y = A0.y + A1.y; R0.z = A0.z + A1.z; R0.w = A0.w + A1.w;
    R1.x = B0.x + B1.x; R1.y = B0.y + B1.y; R1.z = B0.z + B1.z; R1.w = B0.w + B1.w;
    #pragma unroll
    for (int o = 8; o <= 32; o <<= 1) {
        R0.x += __shfl_xor(R0.x, o); R0.y += __shfl_xor(R0.y, o);
        R0.z += __shfl_xor(R0.z, o); R0.w += __shfl_xor(R0.w, o);
        R1.x += __shfl_xor(R1.x, o); R1.y += __shfl_xor(R1.y, o);
        R1.z += __shfl_xor(R1.z, o); R1.w += __shfl_xor(R1.w, o);
    }
}

// ---------- fused layer-1 gather + ReLU + GEMM2 epilogue ----------
// h2_lin'[node] = (relu(dn*(sum+self)+b1) @ W2) * dn -> bf16. W2 staged in LDS
// [k][c] (2-way banks = free); per-wave row broadcast via LDS (same-wave RAW).
__global__ __launch_bounds__(THREADS) void
k_gath_fc2(const ushort* __restrict__ H, const int* __restrict__ csr,
           const int* __restrict__ off, const float* __restrict__ dinv,
           const float* __restrict__ b1, const float* __restrict__ W2,
           ushort* __restrict__ out, int n) {
    __shared__ float Ws[64 * 64];
    __shared__ float hrow[4][64];
    int tid = threadIdx.x;
    for (int i = tid; i < 64 * 64; i += THREADS) Ws[i] = W2[i];
    __syncthreads();
    int t = blockIdx.x * blockDim.x + tid;
    int node = t >> 6;
    if (node >= n) return;
    int lane = tid & 63;
    int g = lane >> 3, q = lane & 7;
    int nl = tid >> 6;
    float dn = dinv[node];
    float4 R0, R1;
    gather_sum8(H, csr, node, off[node], off[node + 1], g, q, R0, R1);
    if (g == 0) {
        float4 b0 = *(const float4*)(b1 + q * 8);
        float4 bb = *(const float4*)(b1 + q * 8 + 4);
        float4 v0, v1;
        v0.x = R0.x * dn + b0.x; v0.y = R0.y * dn + b0.y;
        v0.z = R0.z * dn + b0.z; v0.w = R0.w * dn + b0.w;
        v1.x = R1.x * dn + bb.x; v1.y = R1.y * dn + bb.y;
        v1.z = R1.z * dn + bb.z; v1.w = R1.w * dn + bb.w;
        v0.x = v0.x > 0.f ? v0.x : 0.f; v0.y = v0.y > 0.f ? v0.y : 0.f;
        v0.z = v0.z > 0.f ? v0.z : 0.f; v0.w = v0.w > 0.f ? v0.w : 0.f;
        v1.x = v1.x > 0.f ? v1.x : 0.f; v1.y = v1.y > 0.f ? v1.y : 0.f;
        v1.z = v1.z > 0.f ? v1.z : 0.f; v1.w = v1.w > 0.f ? v1.w : 0.f;
        *(float4*)&hrow[nl][q * 8]     = v0;   // same-wave LDS RAW: hw-ordered
        *(float4*)&hrow[nl][q * 8 + 4] = v1;
    }
    // FC2: lane c computes (h1 @ W2)[c] * dn
    float acc = 0.f;
    #pragma unroll 16
    for (int k = 0; k < 64; ++k)
        acc = fmaf(hrow[nl][k], Ws[k * 64 + lane], acc);
    acc *= dn;
    float other = __shfl_xor(acc, 1);
    if ((lane & 1) == 0)
        *(unsigned*)(out + ((size_t)node << 6) + lane) = pack2(acc, other);
}

// ---------- layer-2: gather + ReLU + fused FC(64->16) + 16-dim pool scatter ----
__global__ void k_gcn_gather_fc(const ushort* __restrict__ H, const int* __restrict__ csr,
                                const int* __restrict__ off, const float* __restrict__ dinv,
                                const float* __restrict__ b, const float* __restrict__ Wfc,
                                const int* __restrict__ dict, float* __restrict__ pool16,
                                int n) {
    __shared__ float wt[16 * 65];     // Wfc transposed [r][c], pad 65
    __shared__ float hrow[4][64];
    int tid = threadIdx.x;
    for (int i = tid; i < 64 * 16; i += THREADS) {
        int cc = i >> 4, r = i & 15;
        wt[r * 65 + cc] = Wfc[i];     // Wfc[cc*16 + r]
    }
    __syncthreads();
    int t = blockIdx.x * blockDim.x + tid;
    int node = t >> 6;
    int lane = tid & 63;
    int g = lane >> 3, q = lane & 7;
    int nl = tid >> 6;
    if (node < n) {
        float dn = dinv[node];
        float4 R0, R1;
        gather_sum8(H, csr, node, off[node], off[node + 1], g, q, R0, R1);
        if (g == 0) {
            float4 b0 = *(const float4*)(b + q * 8);
            float4 b1 = *(const float4*)(b + q * 8 + 4);
            float4 v0, v1;
            v0.x = R0.x * dn + b0.x; v0.y = R0.y * dn + b0.y;
            v0.z = R0.z * dn + b0.z; v0.w = R0.w * dn + b0.w;
            v1.x = R1.x * dn + b1.x; v1.y = R1.y * dn + b1.y;
            v1.z = R1.z * dn + b1.z; v1.w = R1.w * dn + b1.w;
            v0.x = v0.x > 0.f ? v0.x : 0.f; v0.y = v0.y > 0.f ? v0.y : 0.f;
            v0.z = v0.z > 0.f ? v0.z : 0.f; v0.w = v0.w > 0.f ? v0.w : 0.f;
            v1.x = v1.x > 0.f ? v1.x : 0.f; v1.y = v1.y > 0.f ? v1.y : 0.f;
            v1.z = v1.z > 0.f ? v1.z : 0.f; v1.w = v1.w > 0.f ? v1.w : 0.f;
            *(float4*)&hrow[nl][q * 8]     = v0;
            *(float4*)&hrow[nl][q * 8 + 4] = v1;
        }
        int g2 = lane >> 4, r = lane & 15;
        float p = 0.f;
        #pragma unroll
        for (int i = 0; i < 16; ++i) {
            int cc = g2 * 16 + i;
            p = fmaf(hrow[nl][cc], wt[r * 65 + cc], p);
        }
        p += __shfl_xor(p, 16);
        p += __shfl_xor(p, 32);
        if (g2 == 0)
            atomicAdd(&pool16[(size_t)dict[node] * 16 + r], p);
    }
}

// ---------- mean + bias + log_softmax over 16 classes ----------
__global__ void k_final16(const float* __restrict__ pool16, const float* __restrict__ cnt,
                          const float* __restrict__ bfc, float* __restrict__ out, int n) {
    int tid = threadIdx.x;
    int nl = tid >> 4, lane = tid & 15;
    int node = blockIdx.x * 16 + nl;
    if (node >= n) return;
    float inv = 1.0f / fmaxf(cnt[node], 1.0f);
    float acc = pool16[(size_t)node * 16 + lane] * inv + bfc[lane];
    float m = acc;
    for (int o = 8; o; o >>= 1) m = fmaxf(m, __shfl_xor(m, o, 16));
    float ex = __expf(acc - m);
    float s = ex;
    for (int o = 8; o; o >>= 1) s += __shfl_xor(s, o, 16);
    out[(size_t)node * 16 + lane] = acc - m - __logf(s);
}

extern "C" void kernel_launch(void* const* d_in, const int* in_sizes, int n_in,
                              void* d_out, int out_size, void* d_ws, size_t ws_size,
                              hipStream_t stream) {
    const float* x    = (const float*)d_in[0];
    const int*   ei   = (const int*)d_in[1];
    const int*   dict = (const int*)d_in[2];
    const float* W1   = (const float*)d_in[3];
    const float* b1   = (const float*)d_in[4];
    const float* W2   = (const float*)d_in[5];
    const float* b2   = (const float*)d_in[6];
    const float* Wfc  = (const float*)d_in[7];
    const float* bfc  = (const float*)d_in[8];

    const int N  = in_sizes[2];          // 100000
    const int E  = in_sizes[1] / 2;      // 1600000
    const int IN = in_sizes[0] / N;      // 128
    const int* src = ei;
    const int* dst = ei + E;

    // workspace layout (~46 MB)
    ushort* bufA   = (ushort*)d_ws;                // N*64 bf16
    ushort* bufB   = bufA + (size_t)N * 64;        // N*64 bf16
    float* dinv    = (float*)(bufB + (size_t)N * 64);  // N
    int*   deg     = (int*)(dinv + N);             // N
    float* cnt     = (float*)(deg + N);            // N
    int*   off     = (int*)(cnt + N);              // N+1
    int*   bsum    = off + (N + 1);                // 512
    int*   rank    = bsum + 512;                   // E
    int*   csr     = rank + E;                     // E
    float* pool16  = (float*)(csr + E);            // N*16

    const int gN     = (N + THREADS - 1) / THREADS;          // 391
    const int gNE    = (N * 64 + THREADS - 1) / THREADS;     // 25000
    const int gTile  = (N + 63) / 64;                        // 1563
    const int gRows  = (N + 15) / 16;                        // 6250
    const int nDeg   = 2048;
    const int nCnt   = 128;
    const int nBkt   = 1024;
    const int nScale = (N * 8 + THREADS - 1) / THREADS;      // 3125

    hipMemsetAsync(deg, 0, (size_t)N * sizeof(int), stream);
    hipMemsetAsync(cnt, 0, (size_t)N * sizeof(float), stream);
    hipMemsetAsync(pool16, 0, (size_t)N * 16 * sizeof(float), stream);

    // F1: interleaved GEMM1(unscaled) + deg/rank + cnt
    k_f1<<<gTile + nDeg + nCnt, THREADS, 0, stream>>>(x, W1, bufA, N, IN, gTile,
                                                      dst, deg, rank, E, nDeg,
                                                      dict, cnt, nCnt);
    // scans -> off, dinv
    k_bsum<<<gN, THREADS, 0, stream>>>(deg, bsum, N);
    k_bscan<<<1, 512, 0, stream>>>(bsum, gN);
    k_offsets<<<gN, THREADS, 0, stream>>>(deg, bsum, off, dinv, N, E);

    // F2: bucket + scale bufA rows by dinv
    k_f2<<<nBkt + nScale, THREADS, 0, stream>>>(src, dst, rank, off, csr, E,
                                                bufA, dinv, N, nBkt, nScale);

    // fused layer-1 gather + ReLU + GEMM2 -> bufB = h2_lin' bf16
    k_gath_fc2<<<gNE, THREADS, 0, stream>>>(bufA, csr, off, dinv, b1, W2, bufB, N);

    // layer 2: fused gather+ReLU+FC+pool
    k_gcn_gather_fc<<<gNE, THREADS, 0, stream>>>(bufB, csr, off, dinv, b2, Wfc,
                                                 dict, pool16, N);

    // mean + bias + log_softmax
    k_final16<<<gRows, THREADS, 0, stream>>>(pool16, cnt, bfc, (float*)d_out, N);
}

// Round 12
// 357.789 us; speedup vs baseline: 1.0694x; 1.0694x over previous
//
#include <hip/hip_runtime.h>

#define THREADS 256
#define KC 32

// ---- bf16 helpers ----
__device__ inline ushort f2bf(float v) {
    union { float f; unsigned u; } a; a.f = v;
    unsigned r = a.u + 0x7fff + ((a.u >> 16) & 1);
    return (ushort)(r >> 16);
}
__device__ inline unsigned pack2(float a, float b) {
    return (unsigned)f2bf(a) | ((unsigned)f2bf(b) << 16);
}
__device__ inline float bflo(unsigned v) {
    union { unsigned u; float f; } a; a.u = v << 16; return a.f;
}
__device__ inline float bfhi(unsigned v) {
    union { unsigned u; float f; } a; a.u = v & 0xffff0000u; return a.f;
}

// ---------- F1: interleaved [GEMM1 unscaled] x [deg+rank] + [cnt] ----------
__global__ __launch_bounds__(THREADS) void
k_f1(const float* __restrict__ X, const float* __restrict__ W,
     ushort* __restrict__ C, int n, int fin, int nGemm,
     const int* __restrict__ dst, int* __restrict__ deg, int* __restrict__ rank,
     int E, int nDeg,
     const int* __restrict__ dict, float* __restrict__ cnt, int nCnt) {
    int bid = blockIdx.x, tid = threadIdx.x;
    bool isGemm = (bid & 1) && (bid >> 1) < nGemm;
    if (!isGemm) {
        int idx = (bid < 2 * nGemm) ? (bid >> 1) : (bid - nGemm);
        if (idx < nDeg) {
            int stride = nDeg * THREADS;
            for (int e = idx * THREADS + tid; e < E; e += stride)
                rank[e] = atomicAdd(&deg[dst[e]], 1);
        } else {
            int stride = nCnt * THREADS;
            for (int i = (idx - nDeg) * THREADS + tid; i < n; i += stride)
                atomicAdd(&cnt[dict[i]], 1.0f);
        }
        return;
    }
    __shared__ float Xs[KC][68];
    __shared__ float Ws[KC][64];
    int r0  = (bid >> 1) * 64;
    int tx4 = (tid & 15) * 4;
    int ty4 = (tid >> 4) * 4;
    int sxr = tid >> 2, sxk = (tid & 3) * 4;
    int swk = tid >> 4, swc = (tid & 15) * 4;
    int xrow = r0 + sxr; if (xrow >= n) xrow = n - 1;
    const float* xptr = X + (size_t)xrow * fin;
    float4 acc0 = {0,0,0,0}, acc1 = {0,0,0,0}, acc2 = {0,0,0,0}, acc3 = {0,0,0,0};
    for (int kc = 0; kc < fin; kc += KC) {
        float4 xa = *(const float4*)(xptr + kc + sxk);
        float4 xb = *(const float4*)(xptr + kc + 16 + sxk);
        float4 wa = *(const float4*)(W + (size_t)(kc + swk) * 64 + swc);
        float4 wb = *(const float4*)(W + (size_t)(kc + swk + 16) * 64 + swc);
        __syncthreads();
        Xs[sxk + 0][sxr] = xa.x; Xs[sxk + 1][sxr] = xa.y;
        Xs[sxk + 2][sxr] = xa.z; Xs[sxk + 3][sxr] = xa.w;
        Xs[16 + sxk + 0][sxr] = xb.x; Xs[16 + sxk + 1][sxr] = xb.y;
        Xs[16 + sxk + 2][sxr] = xb.z; Xs[16 + sxk + 3][sxr] = xb.w;
        *(float4*)&Ws[swk][swc]      = wa;
        *(float4*)&Ws[swk + 16][swc] = wb;
        __syncthreads();
        #pragma unroll 8
        for (int k = 0; k < KC; ++k) {
            float4 a = *(const float4*)&Xs[k][ty4];
            float4 b = *(const float4*)&Ws[k][tx4];
            acc0.x = fmaf(a.x, b.x, acc0.x); acc0.y = fmaf(a.x, b.y, acc0.y);
            acc0.z = fmaf(a.x, b.z, acc0.z); acc0.w = fmaf(a.x, b.w, acc0.w);
            acc1.x = fmaf(a.y, b.x, acc1.x); acc1.y = fmaf(a.y, b.y, acc1.y);
            acc1.z = fmaf(a.y, b.z, acc1.z); acc1.w = fmaf(a.y, b.w, acc1.w);
            acc2.x = fmaf(a.z, b.x, acc2.x); acc2.y = fmaf(a.z, b.y, acc2.y);
            acc2.z = fmaf(a.z, b.z, acc2.z); acc2.w = fmaf(a.z, b.w, acc2.w);
            acc3.x = fmaf(a.w, b.x, acc3.x); acc3.y = fmaf(a.w, b.y, acc3.y);
            acc3.z = fmaf(a.w, b.z, acc3.z); acc3.w = fmaf(a.w, b.w, acc3.w);
        }
    }
    int row = r0 + ty4;
    #pragma unroll
    for (int r = 0; r < 4; ++r) {
        if (row + r >= n) break;
        float4 a = r == 0 ? acc0 : r == 1 ? acc1 : r == 2 ? acc2 : acc3;
        ushort4 o;
        o.x = f2bf(a.x); o.y = f2bf(a.y); o.z = f2bf(a.z); o.w = f2bf(a.w);
        *(ushort4*)(C + (size_t)(row + r) * 64 + tx4) = o;
    }
}

// ---------- scans ----------
__global__ void k_bsum(const int* __restrict__ deg, int* __restrict__ bsum, int n) {
    __shared__ int s[THREADS];
    int i = blockIdx.x * THREADS + threadIdx.x;
    s[threadIdx.x] = (i < n) ? deg[i] : 0;
    __syncthreads();
    for (int o = THREADS / 2; o; o >>= 1) {
        if (threadIdx.x < o) s[threadIdx.x] += s[threadIdx.x + o];
        __syncthreads();
    }
    if (threadIdx.x == 0) bsum[blockIdx.x] = s[0];
}

// single block of 512; nb <= 512 (nb = 391 here)
__global__ void k_bscan(int* __restrict__ bsum, int nb) {
    __shared__ int s[512];
    int v = (threadIdx.x < nb) ? bsum[threadIdx.x] : 0;
    s[threadIdx.x] = v;
    __syncthreads();
    for (int o = 1; o < 512; o <<= 1) {
        int t = (threadIdx.x >= (unsigned)o) ? s[threadIdx.x - o] : 0;
        __syncthreads();
        s[threadIdx.x] += t;
        __syncthreads();
    }
    if (threadIdx.x < nb) bsum[threadIdx.x] = s[threadIdx.x] - v;  // exclusive
}

__global__ void k_offsets(const int* __restrict__ deg, const int* __restrict__ bsum,
                          int* __restrict__ off, float* __restrict__ dinv, int n, int E) {
    __shared__ int s[THREADS];
    int i = blockIdx.x * THREADS + threadIdx.x;
    int v = (i < n) ? deg[i] : 0;
    s[threadIdx.x] = v;
    __syncthreads();
    for (int o = 1; o < THREADS; o <<= 1) {
        int t = (threadIdx.x >= (unsigned)o) ? s[threadIdx.x - o] : 0;
        __syncthreads();
        s[threadIdx.x] += t;
        __syncthreads();
    }
    if (i < n) {
        off[i] = bsum[blockIdx.x] + s[threadIdx.x] - v;
        dinv[i] = rsqrtf((float)v + 1.0f);
        if (i == n - 1) off[n] = E;
    }
}

// ---------- F2: [bucket] + [scale bufA rows by dinv] ----------
__global__ void k_f2(const int* __restrict__ src, const int* __restrict__ dst,
                     const int* __restrict__ rank, const int* __restrict__ off,
                     int* __restrict__ csr, int E,
                     ushort* __restrict__ A, const float* __restrict__ dinv, int n,
                     int nBkt, int nScale) {
    int bid = blockIdx.x, tid = threadIdx.x;
    if (bid < nBkt) {
        int stride = nBkt * THREADS;
        for (int e = bid * THREADS + tid; e < E; e += stride)
            csr[off[dst[e]] + rank[e]] = src[e];
    } else {
        int t = (bid - nBkt) * THREADS + tid;    // one uint4 (8 bf16) per thread
        if (t < n * 8) {
            float dn = dinv[t >> 3];
            uint4 v = *(const uint4*)(A + (size_t)t * 8);
            uint4 o;
            o.x = pack2(bflo(v.x) * dn, bfhi(v.x) * dn);
            o.y = pack2(bflo(v.y) * dn, bfhi(v.y) * dn);
            o.z = pack2(bflo(v.z) * dn, bfhi(v.z) * dn);
            o.w = pack2(bflo(v.w) * dn, bfhi(v.w) * dn);
            *(uint4*)(A + (size_t)t * 8) = o;
        }
    }
}

// ---------- MLP gather core: wave = 1 node, 8 rows/instr, csr prefetch ----------
__device__ inline void gather_sum8(const ushort* __restrict__ H,
                                   const int* __restrict__ csr,
                                   int node, int j, int end, int g, int q,
                                   float4& R0, float4& R1) {
    float4 A0 = {0,0,0,0}, B0 = {0,0,0,0}, A1 = {0,0,0,0}, B1 = {0,0,0,0};
    if (g == 0) {  // self row joins slot 0
        uint4 sv = *(const uint4*)(H + ((size_t)node << 6) + q * 8);
        A0.x += bflo(sv.x); A0.y += bfhi(sv.x); A0.z += bflo(sv.y); A0.w += bfhi(sv.y);
        B0.x += bflo(sv.z); B0.y += bfhi(sv.z); B0.z += bflo(sv.w); B0.w += bfhi(sv.w);
    }
    int p0 = 0, p1 = 0;
    if (j + 16 <= end) { p0 = csr[j + g]; p1 = csr[j + 8 + g]; }
    while (j + 16 <= end) {
        int s0 = p0, s1 = p1;
        int jn = j + 16;
        if (jn + 16 <= end) { p0 = csr[jn + g]; p1 = csr[jn + 8 + g]; }  // prefetch
        uint4 v0 = *(const uint4*)(H + ((size_t)s0 << 6) + q * 8);
        uint4 v1 = *(const uint4*)(H + ((size_t)s1 << 6) + q * 8);
        A0.x += bflo(v0.x); A0.y += bfhi(v0.x); A0.z += bflo(v0.y); A0.w += bfhi(v0.y);
        B0.x += bflo(v0.z); B0.y += bfhi(v0.z); B0.z += bflo(v0.w); B0.w += bfhi(v0.w);
        A1.x += bflo(v1.x); A1.y += bfhi(v1.x); A1.z += bflo(v1.y); A1.w += bfhi(v1.y);
        B1.x += bflo(v1.z); B1.y += bfhi(v1.z); B1.z += bflo(v1.w); B1.w += bfhi(v1.w);
        j = jn;
    }
    if (j + 8 <= end) {
        int s0 = csr[j + g];
        uint4 v0 = *(const uint4*)(H + ((size_t)s0 << 6) + q * 8);
        A0.x += bflo(v0.x); A0.y += bfhi(v0.x); A0.z += bflo(v0.y); A0.w += bfhi(v0.y);
        B0.x += bflo(v0.z); B0.y += bfhi(v0.z); B0.z += bflo(v0.w); B0.w += bfhi(v0.w);
        j += 8;
    }
    if (g < end - j) {
        int s1 = csr[j + g];
        uint4 v1 = *(const uint4*)(H + ((size_t)s1 << 6) + q * 8);
        A1.x += bflo(v1.x); A1.y += bfhi(v1.x); A1.z += bflo(v1.y); A1.w += bfhi(v1.y);
        B1.x += bflo(v1.z); B1.y += bfhi(v1.z); B1.z += bflo(v1.w); B1.w += bfhi(v1.w);
    }
    R0.x = A0.x + A1.x; R0.y = A0.y + A1.y; R0.z = A0.z + A1.z; R0.w = A0.w + A1.w;
    R1.x = B0.x + B1.x; R1.y = B0.y + B1.y; R1.z = B0.z + B1.z; R1.w = B0.w + B1.w;
    #pragma unroll
    for (int o = 8; o <= 32; o <<= 1) {
        R0.x += __shfl_xor(R0.x, o); R0.y += __shfl_xor(R0.y, o);
        R0.z += __shfl_xor(R0.z, o); R0.w += __shfl_xor(R0.w, o);
        R1.x += __shfl_xor(R1.x, o); R1.y += __shfl_xor(R1.y, o);
        R1.z += __shfl_xor(R1.z, o); R1.w += __shfl_xor(R1.w, o);
    }
}

// layer-1 gather body for one node (64 lanes)
__device__ inline void do_gather_l1(const ushort* __restrict__ H,
                                    const int* __restrict__ csr,
                                    const int* __restrict__ off,
                                    const float* __restrict__ dinv,
                                    const float* __restrict__ b,
                                    ushort* __restrict__ out, int node, int lane) {
    int g = lane >> 3, q = lane & 7;
    float dn = dinv[node];
    float4 R0, R1;
    gather_sum8(H, csr, node, off[node], off[node + 1], g, q, R0, R1);
    if (g == 0) {
        float4 b0 = *(const float4*)(b + q * 8);
        float4 b1 = *(const float4*)(b + q * 8 + 4);
        float v0 = R0.x * dn + b0.x, v1 = R0.y * dn + b0.y;
        float v2 = R0.z * dn + b0.z, v3 = R0.w * dn + b0.w;
        float v4 = R1.x * dn + b1.x, v5 = R1.y * dn + b1.y;
        float v6 = R1.z * dn + b1.z, v7 = R1.w * dn + b1.w;
        uint4 o;
        o.x = pack2(v0 > 0.f ? v0 : 0.f, v1 > 0.f ? v1 : 0.f);
        o.y = pack2(v2 > 0.f ? v2 : 0.f, v3 > 0.f ? v3 : 0.f);
        o.z = pack2(v4 > 0.f ? v4 : 0.f, v5 > 0.f ? v5 : 0.f);
        o.w = pack2(v6 > 0.f ? v6 : 0.f, v7 > 0.f ? v7 : 0.f);
        *(uint4*)(out + ((size_t)node << 6) + q * 8) = o;
    }
}

// register-blocked bf16 GEMM tile body (needs caller's LDS)
__device__ inline void do_gemm_bf16(float (*Xs)[68], float (*Ws)[64],
                                    const ushort* __restrict__ X,
                                    const float* __restrict__ W,
                                    const float* __restrict__ dinv,
                                    ushort* __restrict__ C, int n, int fin,
                                    int r0, int tid) {
    int tx4 = (tid & 15) * 4;
    int ty4 = (tid >> 4) * 4;
    int sxr = tid >> 2, sk8 = (tid & 3) * 8;
    int swk = tid >> 4, swc = (tid & 15) * 4;
    int xrow = r0 + sxr; if (xrow >= n) xrow = n - 1;
    const ushort* xptr = X + (size_t)xrow * fin;
    float4 acc0 = {0,0,0,0}, acc1 = {0,0,0,0}, acc2 = {0,0,0,0}, acc3 = {0,0,0,0};
    for (int kc = 0; kc < fin; kc += KC) {
        uint4 xv = *(const uint4*)(xptr + kc + sk8);
        float4 wa = *(const float4*)(W + (size_t)(kc + swk) * 64 + swc);
        float4 wb = *(const float4*)(W + (size_t)(kc + swk + 16) * 64 + swc);
        __syncthreads();
        Xs[sk8 + 0][sxr] = bflo(xv.x); Xs[sk8 + 1][sxr] = bfhi(xv.x);
        Xs[sk8 + 2][sxr] = bflo(xv.y); Xs[sk8 + 3][sxr] = bfhi(xv.y);
        Xs[sk8 + 4][sxr] = bflo(xv.z); Xs[sk8 + 5][sxr] = bfhi(xv.z);
        Xs[sk8 + 6][sxr] = bflo(xv.w); Xs[sk8 + 7][sxr] = bfhi(xv.w);
        *(float4*)&Ws[swk][swc]      = wa;
        *(float4*)&Ws[swk + 16][swc] = wb;
        __syncthreads();
        #pragma unroll 8
        for (int k = 0; k < KC; ++k) {
            float4 a = *(const float4*)&Xs[k][ty4];
            float4 b = *(const float4*)&Ws[k][tx4];
            acc0.x = fmaf(a.x, b.x, acc0.x); acc0.y = fmaf(a.x, b.y, acc0.y);
            acc0.z = fmaf(a.x, b.z, acc0.z); acc0.w = fmaf(a.x, b.w, acc0.w);
            acc1.x = fmaf(a.y, b.x, acc1.x); acc1.y = fmaf(a.y, b.y, acc1.y);
            acc1.z = fmaf(a.y, b.z, acc1.z); acc1.w = fmaf(a.y, b.w, acc1.w);
            acc2.x = fmaf(a.z, b.x, acc2.x); acc2.y = fmaf(a.z, b.y, acc2.y);
            acc2.z = fmaf(a.z, b.z, acc2.z); acc2.w = fmaf(a.z, b.w, acc2.w);
            acc3.x = fmaf(a.w, b.x, acc3.x); acc3.y = fmaf(a.w, b.y, acc3.y);
            acc3.z = fmaf(a.w, b.z, acc3.z); acc3.w = fmaf(a.w, b.w, acc3.w);
        }
    }
    int row = r0 + ty4;
    #pragma unroll
    for (int r = 0; r < 4; ++r) {
        if (row + r >= n) break;
        float dn = dinv[row + r];
        float4 a = r == 0 ? acc0 : r == 1 ? acc1 : r == 2 ? acc2 : acc3;
        ushort4 o;
        o.x = f2bf(a.x * dn); o.y = f2bf(a.y * dn);
        o.z = f2bf(a.z * dn); o.w = f2bf(a.w * dn);
        *(ushort4*)(C + (size_t)(row + r) * 64 + tx4) = o;
    }
}

// ---------- d1/d3: plain kernels ----------
__global__ void k_gather_l1(const ushort* __restrict__ H, const int* __restrict__ csr,
                            const int* __restrict__ off, const float* __restrict__ dinv,
                            const float* __restrict__ b, ushort* __restrict__ out,
                            int n, int nodeBase) {
    int node = nodeBase + ((blockIdx.x * blockDim.x + threadIdx.x) >> 6);
    if (node >= n) return;
    do_gather_l1(H, csr, off, dinv, b, out, node, threadIdx.x & 63);
}

__global__ __launch_bounds__(THREADS) void
k_gemm_bf16(const ushort* __restrict__ X, const float* __restrict__ W,
            const float* __restrict__ dinv, ushort* __restrict__ C,
            int n, int fin, int tileBase) {
    __shared__ float Xs[KC][68];
    __shared__ float Ws[KC][64];
    do_gemm_bf16(Xs, Ws, X, W, dinv, C, n, fin,
                 (blockIdx.x + tileBase) * 64, threadIdx.x);
}

// ---------- d2: interleaved [gather1 second half] x [GEMM2 first half] ----------
__global__ __launch_bounds__(THREADS) void
k_d2(const ushort* __restrict__ A, const int* __restrict__ csr,
     const int* __restrict__ off, const float* __restrict__ dinv,
     const float* __restrict__ b1, ushort* __restrict__ B,   // gather: A->B
     const float* __restrict__ W2, ushort* __restrict__ C,   // gemm:  B->C
     int n, int nodeBase, int nGem2) {
    __shared__ float Xs[KC][68];
    __shared__ float Ws[KC][64];
    int bid = blockIdx.x, tid = threadIdx.x;
    bool isGemm = (bid & 1) && (bid >> 1) < nGem2;
    if (isGemm) {
        do_gemm_bf16(Xs, Ws, B, W2, dinv, C, n, 64, (bid >> 1) * 64, tid);
        return;
    }
    int idx = (bid < 2 * nGem2) ? (bid >> 1) : (bid - nGem2);
    int node = nodeBase + idx * 4 + (tid >> 6);
    if (node >= n) return;
    do_gather_l1(A, csr, off, dinv, b1, B, node, tid & 63);
}

// ---------- layer-2: gather + ReLU + fused FC(64->16) + 16-dim pool scatter ----
__global__ void k_gcn_gather_fc(const ushort* __restrict__ H, const int* __restrict__ csr,
                                const int* __restrict__ off, const float* __restrict__ dinv,
                                const float* __restrict__ b, const float* __restrict__ Wfc,
                                const int* __restrict__ dict, float* __restrict__ pool16,
                                int n) {
    __shared__ float wt[16 * 65];     // Wfc transposed [r][c], pad 65
    __shared__ float hrow[4][64];
    int tid = threadIdx.x;
    for (int i = tid; i < 64 * 16; i += THREADS) {
        int cc = i >> 4, r = i & 15;
        wt[r * 65 + cc] = Wfc[i];     // Wfc[cc*16 + r]
    }
    __syncthreads();
    int t = blockIdx.x * blockDim.x + tid;
    int node = t >> 6;
    int lane = tid & 63;
    int g = lane >> 3, q = lane & 7;
    int nl = tid >> 6;
    if (node < n) {
        float dn = dinv[node];
        float4 R0, R1;
        gather_sum8(H, csr, node, off[node], off[node + 1], g, q, R0, R1);
        if (g == 0) {
            float4 b0 = *(const float4*)(b + q * 8);
            float4 b1 = *(const float4*)(b + q * 8 + 4);
            float4 v0, v1;
            v0.x = R0.x * dn + b0.x; v0.y = R0.y * dn + b0.y;
            v0.z = R0.z * dn + b0.z; v0.w = R0.w * dn + b0.w;
            v1.x = R1.x * dn + b1.x; v1.y = R1.y * dn + b1.y;
            v1.z = R1.z * dn + b1.z; v1.w = R1.w * dn + b1.w;
            v0.x = v0.x > 0.f ? v0.x : 0.f; v0.y = v0.y > 0.f ? v0.y : 0.f;
            v0.z = v0.z > 0.f ? v0.z : 0.f; v0.w = v0.w > 0.f ? v0.w : 0.f;
            v1.x = v1.x > 0.f ? v1.x : 0.f; v1.y = v1.y > 0.f ? v1.y : 0.f;
            v1.z = v1.z > 0.f ? v1.z : 0.f; v1.w = v1.w > 0.f ? v1.w : 0.f;
            *(float4*)&hrow[nl][q * 8]     = v0;   // same-wave LDS RAW: hw-ordered
            *(float4*)&hrow[nl][q * 8 + 4] = v1;
        }
        int g2 = lane >> 4, r = lane & 15;
        float p = 0.f;
        #pragma unroll
        for (int i = 0; i < 16; ++i) {
            int cc = g2 * 16 + i;
            p = fmaf(hrow[nl][cc], wt[r * 65 + cc], p);
        }
        p += __shfl_xor(p, 16);
        p += __shfl_xor(p, 32);
        if (g2 == 0)
            atomicAdd(&pool16[(size_t)dict[node] * 16 + r], p);
    }
}

// ---------- mean + bias + log_softmax over 16 classes ----------
__global__ void k_final16(const float* __restrict__ pool16, const float* __restrict__ cnt,
                          const float* __restrict__ bfc, float* __restrict__ out, int n) {
    int tid = threadIdx.x;
    int nl = tid >> 4, lane = tid & 15;
    int node = blockIdx.x * 16 + nl;
    if (node >= n) return;
    float inv = 1.0f / fmaxf(cnt[node], 1.0f);
    float acc = pool16[(size_t)node * 16 + lane] * inv + bfc[lane];
    float m = acc;
    for (int o = 8; o; o >>= 1) m = fmaxf(m, __shfl_xor(m, o, 16));
    float ex = __expf(acc - m);
    float s = ex;
    for (int o = 8; o; o >>= 1) s += __shfl_xor(s, o, 16);
    out[(size_t)node * 16 + lane] = acc - m - __logf(s);
}

extern "C" void kernel_launch(void* const* d_in, const int* in_sizes, int n_in,
                              void* d_out, int out_size, void* d_ws, size_t ws_size,
                              hipStream_t stream) {
    const float* x    = (const float*)d_in[0];
    const int*   ei   = (const int*)d_in[1];
    const int*   dict = (const int*)d_in[2];
    const float* W1   = (const float*)d_in[3];
    const float* b1   = (const float*)d_in[4];
    const float* W2   = (const float*)d_in[5];
    const float* b2   = (const float*)d_in[6];
    const float* Wfc  = (const float*)d_in[7];
    const float* bfc  = (const float*)d_in[8];

    const int N  = in_sizes[2];          // 100000
    const int E  = in_sizes[1] / 2;      // 1600000
    const int IN = in_sizes[0] / N;      // 128
    const int* src = ei;
    const int* dst = ei + E;

    // workspace layout (~59 MB)
    ushort* bufA   = (ushort*)d_ws;                    // N*64 bf16 (h1_lin')
    ushort* bufB   = bufA + (size_t)N * 64;            // N*64 bf16 (h1)
    ushort* bufC   = bufB + (size_t)N * 64;            // N*64 bf16 (h2_lin')
    float* dinv    = (float*)(bufC + (size_t)N * 64);  // N
    int*   deg     = (int*)(dinv + N);                 // N
    float* cnt     = (float*)(deg + N);                // N
    int*   off     = (int*)(cnt + N);                  // N+1
    int*   bsum    = off + (N + 1);                    // 512
    int*   rank    = bsum + 512;                       // E
    int*   csr     = rank + E;                         // E
    float* pool16  = (float*)(csr + E);                // N*16

    const int gN     = (N + THREADS - 1) / THREADS;          // 391
    const int gNE    = (N * 64 + THREADS - 1) / THREADS;     // 25000
    const int gTile  = (N + 63) / 64;                        // 1563
    const int gRows  = (N + 15) / 16;                        // 6250
    const int nDeg   = 2048;
    const int nCnt   = 128;
    const int nBkt   = 1024;
    const int nScale = (N * 8 + THREADS - 1) / THREADS;      // 3125

    // pipeline split: first half = nGem2 tiles worth of nodes
    const int nGem2 = (gTile + 1) / 2;          // 782 tiles
    const int N1    = nGem2 * 64;               // 50048 nodes
    const int g1a   = (N1 + 3) / 4;             // 12512 gather blocks (d1)
    const int g1b   = (N - N1 + 3) / 4;         // 12488 gather blocks (d2)

    hipMemsetAsync(deg, 0, (size_t)N * sizeof(int), stream);
    hipMemsetAsync(cnt, 0, (size_t)N * sizeof(float), stream);
    hipMemsetAsync(pool16, 0, (size_t)N * 16 * sizeof(float), stream);

    // F1: interleaved GEMM1(unscaled) + deg/rank + cnt
    k_f1<<<gTile + nDeg + nCnt, THREADS, 0, stream>>>(x, W1, bufA, N, IN, gTile,
                                                      dst, deg, rank, E, nDeg,
                                                      dict, cnt, nCnt);
    // scans -> off, dinv
    k_bsum<<<gN, THREADS, 0, stream>>>(deg, bsum, N);
    k_bscan<<<1, 512, 0, stream>>>(bsum, gN);
    k_offsets<<<gN, THREADS, 0, stream>>>(deg, bsum, off, dinv, N, E);

    // F2: bucket + scale bufA rows by dinv
    k_f2<<<nBkt + nScale, THREADS, 0, stream>>>(src, dst, rank, off, csr, E,
                                                bufA, dinv, N, nBkt, nScale);

    // d1: gather1 nodes [0, N1) -> bufB
    k_gather_l1<<<g1a, THREADS, 0, stream>>>(bufA, csr, off, dinv, b1, bufB, N, 0);
    // d2: gather1 nodes [N1, N) interleaved with GEMM2 tiles [0, nGem2) -> bufC
    k_d2<<<g1b + nGem2, THREADS, 0, stream>>>(bufA, csr, off, dinv, b1, bufB,
                                              W2, bufC, N, N1, nGem2);
    // d3: GEMM2 tiles [nGem2, gTile) -> bufC
    k_gemm_bf16<<<gTile - nGem2, THREADS, 0, stream>>>(bufB, W2, dinv, bufC, N, 64, nGem2);

    // layer 2: fused gather+ReLU+FC+pool (reads bufC)
    k_gcn_gather_fc<<<gNE, THREADS, 0, stream>>>(bufC, csr, off, dinv, b2, Wfc,
                                                 dict, pool16, N);

    // mean + bias + log_softmax
    k_final16<<<gRows, THREADS, 0, stream>>>(pool16, cnt, bfc, (float*)d_out, N);
}